// Round 2
// baseline (138959.119 us; speedup 1.0000x reference)
//
#include <hip/hip_runtime.h>
#include <math.h>

#define G_BLOCKS 256
#define NT 256

constexpr int T_STEPS = 600;
constexpr int TXT     = 200;
constexpr int NMEL    = 80;
constexpr int H       = 1024;
constexpr int ATT     = 640;
constexpr int DIN     = H + ATT;   // 1664

// ---- workspace layout (float offsets) ----
constexpr int WS_KEYS = 0;                 // TXT*ATT
constexpr int WS_VALS = WS_KEYS + TXT*ATT; // TXT*ATT
constexpr int WS_X    = WS_VALS + TXT*ATT; // 128 (80 used)
constexpr int WS_HA   = WS_X + 128;        // 2*H ping-pong
constexpr int WS_H0   = WS_HA + 2*H;       // H
constexpr int WS_H1   = WS_H0 + H;         // 2*H ping-pong
constexpr int WS_Q    = WS_H1 + 2*H;       // ATT
constexpr int WS_D1   = WS_Q + ATT;        // H
constexpr int WS_D    = WS_D1 + H;         // H
constexpr int WS_AM   = WS_D + H;          // 8 attn partial max
constexpr int WS_AZ   = WS_AM + 8;         // 8 attn partial sumexp
constexpr int WS_CP   = WS_AZ + 8;         // 8*ATT attn partial ctx
constexpr int WS_BAR  = WS_CP + 8*ATT;     // 4 (uint cnt, gen)
constexpr int WS_END  = WS_BAR + 4;

__device__ __forceinline__ double dsig(double x) { return 1.0 / (1.0 + exp(-x)); }

__device__ __forceinline__ double red16d(double v) {
  v += __shfl_xor(v, 8, 16);
  v += __shfl_xor(v, 4, 16);
  v += __shfl_xor(v, 2, 16);
  v += __shfl_xor(v, 1, 16);
  return v;
}
__device__ __forceinline__ double red64d(double v) {
  #pragma unroll
  for (int off = 32; off > 0; off >>= 1) v += __shfl_xor(v, off, 64);
  return v;
}

// 16-lane strided float4 dot, f64 accumulate (K % 4 == 0); l = 0..15
__device__ __forceinline__ double ddot16(const float* __restrict__ W,
                                         const float* __restrict__ v, int K, int l) {
  const float4* W4 = (const float4*)W;
  const float4* v4 = (const float4*)v;
  double s = 0.0;
  for (int i = l; i < (K >> 2); i += 16) {
    float4 w = W4[i], x = v4[i];
    s = fma((double)w.x, (double)x.x, s); s = fma((double)w.y, (double)x.y, s);
    s = fma((double)w.z, (double)x.z, s); s = fma((double)w.w, (double)x.w, s);
  }
  return s;
}
// 64-lane strided float4 dot, f64 accumulate
__device__ __forceinline__ double ddot64(const float* __restrict__ W,
                                         const float* __restrict__ v, int K, int lane) {
  const float4* W4 = (const float4*)W;
  const float4* v4 = (const float4*)v;
  double s = 0.0;
  for (int i = lane; i < (K >> 2); i += 64) {
    float4 w = W4[i], x = v4[i];
    s = fma((double)w.x, (double)x.x, s); s = fma((double)w.y, (double)x.y, s);
    s = fma((double)w.z, (double)x.z, s); s = fma((double)w.w, (double)x.w, s);
  }
  return s;
}

__device__ __forceinline__ void stage(float* dst, const float* src, int n) {
  float4* d4 = (float4*)dst;
  const float4* s4 = (const float4*)src;
  for (int i = threadIdx.x; i < (n >> 2); i += NT) d4[i] = s4[i];
}

// grid barrier: agent-scope atomics give cross-XCD L2 wb/inv per LLVM memmodel
__device__ __forceinline__ void gridbar(unsigned* bar) {
  __syncthreads();
  if (threadIdx.x == 0) {
    unsigned* cnt = bar;
    unsigned* gen = bar + 1;
    unsigned g = __hip_atomic_load(gen, __ATOMIC_RELAXED, __HIP_MEMORY_SCOPE_AGENT);
    unsigned a = __hip_atomic_fetch_add(cnt, 1u, __ATOMIC_ACQ_REL, __HIP_MEMORY_SCOPE_AGENT);
    if (a == G_BLOCKS - 1) {
      __hip_atomic_store(cnt, 0u, __ATOMIC_RELAXED, __HIP_MEMORY_SCOPE_AGENT);
      __hip_atomic_store(gen, g + 1u, __ATOMIC_RELEASE, __HIP_MEMORY_SCOPE_AGENT);
    } else {
      while (__hip_atomic_load(gen, __ATOMIC_RELAXED, __HIP_MEMORY_SCOPE_AGENT) == g)
        __builtin_amdgcn_s_sleep(1);
      __builtin_amdgcn_fence(__ATOMIC_ACQUIRE, "agent");
    }
  }
  __syncthreads();
}

__global__ void init_ws(float* ws) {
  const int n = WS_END - WS_X;
  for (int i = blockIdx.x * blockDim.x + threadIdx.x; i < n; i += gridDim.x * blockDim.x)
    ws[WS_X + i] = 0.f;
}

__global__ void __launch_bounds__(NT)
ar_persist(const float* __restrict__ residual, const float* __restrict__ text,
           const float* __restrict__ Wih_a, const float* __restrict__ Whh_a, const float* __restrict__ b_a,
           const float* __restrict__ Wq, const float* __restrict__ Wk, const float* __restrict__ Wv,
           const float* __restrict__ v_attn,
           const float* __restrict__ Wih0, const float* __restrict__ Whh0, const float* __restrict__ b0,
           const float* __restrict__ Wih1, const float* __restrict__ Whh1, const float* __restrict__ b1,
           const float* __restrict__ Wd1, const float* __restrict__ bd1,
           const float* __restrict__ Wd2, const float* __restrict__ bd2,
           const float* __restrict__ Wc, const float* __restrict__ bc,
           const float* __restrict__ Wg, const float* __restrict__ bg,
           float* __restrict__ out, float* __restrict__ ws)
{
  const int tid  = threadIdx.x;
  const int b    = blockIdx.x;
  const int g    = tid >> 4;   // 16 groups of 16 lanes
  const int l    = tid & 15;
  const int wave = tid >> 6;   // 4 waves
  const int lane = tid & 63;

  __shared__ float  shv[2048];    // vector staging (two 1024-vecs)
  __shared__ float  shb[ATT];     // q / ctx staging
  __shared__ double zl[16];
  __shared__ double z0part[16];   // persists P2 -> P4
  __shared__ double cA[4], c0S[4], c1S[4];  // cell states (f64), persist all steps
  __shared__ float  sc[32];
  __shared__ double misc[4];

  unsigned* bar = (unsigned*)(ws + WS_BAR);

  if (tid < 4) { cA[tid] = 0.0; c0S[tid] = 0.0; c1S[tid] = 0.0; }

  // ---- pre-phase: keys = text@Wk^T, vals = text@Wv^T ----
  {
    const int gid = b * 16 + g;
    for (int idx = gid; idx < 2 * TXT * ATT; idx += G_BLOCKS * 16) {
      const int which = idx / (TXT * ATT);
      const int rem = idx - which * (TXT * ATT);
      const int t = rem / ATT;
      const int a = rem - t * ATT;
      const float* Wrow = (which ? Wv : Wk) + a * ATT;
      double s = ddot16(Wrow, text + t * ATT, ATT, l);
      s = red16d(s);
      if (l == 0) ws[(which ? WS_VALS : WS_KEYS) + t * ATT + a] = (float)s;
    }
  }
  gridbar(bar);

  const int j0 = b * 4;              // this block's 4 hidden indices
  const int gi = g & 3;              // gate 0=i 1=f 2=g 3=o
  const int jl = g >> 2;             // 0..3
  const int zrow = gi * H + j0 + jl; // row of 4H-dim z

  int pa = 0, p1 = 0;
  double gate_ha = 0.0;

  for (int s = 0; s < T_STEPS; ++s) {
    // ===== P1: z_a = Wih_a@x + Whh_a@ha + b_a -> ha, ca =====
    stage(shv, ws + WS_X, 80);
    stage(shv + 128, ws + WS_HA + pa * H, H);
    __syncthreads();
    {
      double sum = ddot16(Wih_a + zrow * NMEL, shv, NMEL, l)
                 + ddot16(Whh_a + zrow * H, shv + 128, H, l);
      sum = red16d(sum) + (double)b_a[zrow];
      if (l == 0) zl[g] = sum;
    }
    __syncthreads();
    if (tid < 4) {
      double iv = zl[tid*4+0], fv = zl[tid*4+1], gv = zl[tid*4+2], ov = zl[tid*4+3];
      double c = dsig(fv) * cA[tid] + dsig(iv) * tanh(gv);
      double h = dsig(ov) * tanh(c);
      cA[tid] = c;
      ws[WS_HA + (pa ^ 1) * H + j0 + tid] = (float)h;
    }
    pa ^= 1;
    gridbar(bar);

    // ===== P2: z0part = Wih0[:,:H]@ha + Whh0@h0 + b0 ; q = Wq@ha ; gate_ha =====
    stage(shv, ws + WS_HA + pa * H, H);
    stage(shv + 1024, ws + WS_H0, H);
    __syncthreads();
    {
      double sum = ddot16(Wih0 + zrow * DIN, shv, H, l)
                 + ddot16(Whh0 + zrow * H, shv + 1024, H, l);
      sum = red16d(sum) + (double)b0[zrow];
      if (l == 0) z0part[g] = sum;
    }
    if (b < 160) {
      const int qr = b * 4 + wave;
      double s2 = ddot64(Wq + qr * H, shv, H, lane);
      s2 = red64d(s2);
      if (lane == 0) ws[WS_Q + qr] = (float)s2;
    }
    if (b == 160 && wave == 0) {
      double s2 = ddot64(Wg, shv, H, lane);
      gate_ha = red64d(s2);
    }
    gridbar(bar);

    // ===== P3: attention partials (blocks 0..7, 25 positions each) =====
    if (b < 8) {
      stage(shb, ws + WS_Q, ATT);
      __syncthreads();
      for (int lt = wave; lt < 25; lt += 4) {
        const int t = b * 25 + lt;
        const float* krow = ws + WS_KEYS + t * ATT;
        double s2 = 0.0;
        for (int a = lane; a < ATT; a += 64)
          s2 += (double)tanhf(shb[a] + krow[a]) * (double)v_attn[a];
        s2 = red64d(s2);
        if (lane == 0) sc[lt] = (float)s2;
      }
      __syncthreads();
      if (tid == 0) {
        float m = sc[0];
        for (int i = 1; i < 25; ++i) m = fmaxf(m, sc[i]);
        misc[0] = (double)m;
      }
      __syncthreads();
      {
        const float mf = (float)misc[0];
        if (tid < 25) sc[tid] = expf(sc[tid] - mf);
      }
      __syncthreads();
      if (tid == 0) {
        double z = 0.0;
        for (int i = 0; i < 25; ++i) z += (double)sc[i];
        ws[WS_AM + b] = (float)misc[0];
        ws[WS_AZ + b] = (float)z;
      }
      for (int a = tid; a < ATT; a += NT) {
        double acc = 0.0;
        for (int i = 0; i < 25; ++i)
          acc = fma((double)sc[i], (double)ws[WS_VALS + (b * 25 + i) * ATT + a], acc);
        ws[WS_CP + b * ATT + a] = (float)acc;
      }
    }
    gridbar(bar);

    // ===== P4: ctx combine ; z0 finish -> h0 ; gate =====
    {
      double m = (double)ws[WS_AM + 0];
      #pragma unroll
      for (int i = 1; i < 8; ++i) m = fmax(m, (double)ws[WS_AM + i]);
      double wgt[8]; double Zt = 0.0;
      #pragma unroll
      for (int i = 0; i < 8; ++i) {
        wgt[i] = exp((double)ws[WS_AM + i] - m);
        Zt = fma(wgt[i], (double)ws[WS_AZ + i], Zt);
      }
      const double inv = 1.0 / Zt;
      for (int a = tid; a < ATT; a += NT) {
        double c = 0.0;
        #pragma unroll
        for (int i = 0; i < 8; ++i) c = fma(wgt[i], (double)ws[WS_CP + i * ATT + a], c);
        shb[a] = (float)(c * inv);
      }
    }
    __syncthreads();
    {
      double sum = ddot16(Wih0 + zrow * DIN + H, shb, ATT, l);
      sum = red16d(sum) + z0part[g];   // z0part added ONCE, after reduction (was the bug)
      if (l == 0) zl[g] = sum;
    }
    __syncthreads();
    if (tid < 4) {
      double iv = zl[tid*4+0], fv = zl[tid*4+1], gv = zl[tid*4+2], ov = zl[tid*4+3];
      double c = dsig(fv) * c0S[tid] + dsig(iv) * tanh(gv);
      double h = dsig(ov) * tanh(c);
      c0S[tid] = c;
      ws[WS_H0 + j0 + tid] = (float)h;
    }
    if (b == 160 && wave == 0) {
      double s2 = 0.0;
      for (int a = lane; a < ATT; a += 64)
        s2 = fma((double)Wg[H + a], (double)shb[a], s2);
      s2 = red64d(s2);
      if (lane == 0) out[T_STEPS * NMEL + s] = (float)dsig(s2 + gate_ha + (double)bg[0]);
    }
    gridbar(bar);

    // ===== P5: z1 = Wih1@h0 + Whh1@h1 + b1 -> h1 =====
    stage(shv, ws + WS_H0, H);
    stage(shv + 1024, ws + WS_H1 + p1 * H, H);
    __syncthreads();
    {
      double sum = ddot16(Wih1 + zrow * H, shv, H, l)
                 + ddot16(Whh1 + zrow * H, shv + 1024, H, l);
      sum = red16d(sum) + (double)b1[zrow];
      if (l == 0) zl[g] = sum;
    }
    __syncthreads();
    if (tid < 4) {
      double iv = zl[tid*4+0], fv = zl[tid*4+1], gv = zl[tid*4+2], ov = zl[tid*4+3];
      double c = dsig(fv) * c1S[tid] + dsig(iv) * tanh(gv);
      double h = dsig(ov) * tanh(c);
      c1S[tid] = c;
      ws[WS_H1 + (p1 ^ 1) * H + j0 + tid] = (float)h;
    }
    p1 ^= 1;
    gridbar(bar);

    // ===== P6: d1 = tanh(Wd1@h1 + bd1) =====
    stage(shv, ws + WS_H1 + p1 * H, H);
    __syncthreads();
    {
      const int r = b * 4 + wave;
      double s2 = ddot64(Wd1 + r * H, shv, H, lane);
      s2 = red64d(s2) + (double)bd1[r];
      if (lane == 0) ws[WS_D1 + r] = (float)tanh(s2);
    }
    gridbar(bar);

    // ===== P7: d = tanh(Wd2@d1 + bd2) =====
    stage(shv, ws + WS_D1, H);
    __syncthreads();
    {
      const int r = b * 4 + wave;
      double s2 = ddot64(Wd2 + r * H, shv, H, lane);
      s2 = red64d(s2) + (double)bd2[r];
      if (lane == 0) ws[WS_D + r] = (float)tanh(s2);
    }
    gridbar(bar);

    // ===== P8: dec_out rows (b, 80+b) ; out ; next x =====
    if (b < NMEL) {
      stage(shv, ws + WS_D, H);
      __syncthreads();
      if (wave < 2) {
        const int r = wave * NMEL + b;   // wave0: log_s row, wave1: bb row
        double s2 = ddot64(Wc + r * H, shv, H, lane);
        s2 = red64d(s2) + (double)bc[r];
        if (lane == 0) misc[wave] = s2;
      }
      __syncthreads();
      if (tid == 0) {
        const int idx = T_STEPS - 1 - s;
        const double r = (double)residual[idx * NMEL + b];
        const double o = (r - misc[1]) * exp(-misc[0]);
        out[idx * NMEL + b] = (float)o;
        ws[WS_X + b] = (float)o;
      }
    }
    gridbar(bar);
  }
}

extern "C" void kernel_launch(void* const* d_in, const int* in_sizes, int n_in,
                              void* d_out, int out_size, void* d_ws, size_t ws_size,
                              hipStream_t stream) {
  const float* residual = (const float*)d_in[0];
  const float* text   = (const float*)d_in[1];
  const float* Wih_a  = (const float*)d_in[2];
  const float* Whh_a  = (const float*)d_in[3];
  const float* b_a    = (const float*)d_in[4];
  const float* Wq     = (const float*)d_in[5];
  const float* Wk     = (const float*)d_in[6];
  const float* Wv     = (const float*)d_in[7];
  const float* v_attn = (const float*)d_in[8];
  const float* Wih0   = (const float*)d_in[9];
  const float* Whh0   = (const float*)d_in[10];
  const float* b0     = (const float*)d_in[11];
  const float* Wih1   = (const float*)d_in[12];
  const float* Whh1   = (const float*)d_in[13];
  const float* b1     = (const float*)d_in[14];
  const float* Wd1    = (const float*)d_in[15];
  const float* bd1    = (const float*)d_in[16];
  const float* Wd2    = (const float*)d_in[17];
  const float* bd2    = (const float*)d_in[18];
  const float* Wc     = (const float*)d_in[19];
  const float* bc     = (const float*)d_in[20];
  const float* Wg     = (const float*)d_in[21];
  const float* bg     = (const float*)d_in[22];
  float* out = (float*)d_out;
  float* ws  = (float*)d_ws;

  init_ws<<<64, 256, 0, stream>>>(ws);
  ar_persist<<<G_BLOCKS, NT, 0, stream>>>(residual, text, Wih_a, Whh_a, b_a,
      Wq, Wk, Wv, v_attn, Wih0, Whh0, b0, Wih1, Whh1, b1,
      Wd1, bd1, Wd2, bd2, Wc, bc, Wg, bg, out, ws);
}

// Round 3
// 103827.100 us; speedup vs baseline: 1.3384x; 1.3384x over previous
//
#include <hip/hip_runtime.h>
#include <hip/hip_bf16.h>
#include <math.h>

#define GBK 512          // grid blocks (2 per CU, co-resident)
#define NT  512          // threads per block (8 waves)

constexpr int T_STEPS = 600;
constexpr int TXT     = 200;
constexpr int NMEL    = 80;
constexpr int H       = 1024;
constexpr int ATT     = 640;
constexpr int DIN     = H + ATT;   // 1664
constexpr int NGRP    = 16;        // barrier groups
constexpr int GRPSZ   = GBK / NGRP;

// ---- ws layout: bf16 region (ushort element offsets) ----
constexpr size_t O_WQ    = 0;                                  // 640*1024
constexpr size_t O_WIHA  = O_WQ   + (size_t)ATT*H;             // 4096*80
constexpr size_t O_WHHA  = O_WIHA + (size_t)4*H*NMEL;          // 4096*1024
constexpr size_t O_WIH0  = O_WHHA + (size_t)4*H*H;             // 4096*1664
constexpr size_t O_WD1   = O_WIH0 + (size_t)4*H*DIN;           // 1024*1024
constexpr size_t O_WD2   = O_WD1  + (size_t)H*H;
constexpr size_t O_KEYS  = O_WD2  + (size_t)H*H;               // 200*640
constexpr size_t O_VALS  = O_KEYS + (size_t)TXT*ATT;
constexpr size_t O_END_U = O_VALS + (size_t)TXT*ATT;
constexpr size_t FBYTE   = ((O_END_U*2 + 255)/256)*256;        // float region start (bytes)
// ---- float region (float element offsets) ----
constexpr int F_X  = 0;            // 128 (80 used)
constexpr int F_HA = 128;          // 2*H ping-pong
constexpr int F_H0 = F_HA + 2*H;   // H
constexpr int F_H1 = F_H0 + H;     // 2*H ping-pong
constexpr int F_Q  = F_H1 + 2*H;   // ATT
constexpr int F_D1 = F_Q  + ATT;   // H
constexpr int F_D  = F_D1 + H;     // H
constexpr int F_AM = F_D  + H;     // 8
constexpr int F_AZ = F_AM + 8;     // 8
constexpr int F_CP = F_AZ + 8;     // 8*ATT
constexpr int F_END= F_CP + 8*ATT; // = 13072
constexpr size_t BBYTE  = FBYTE + (((size_t)F_END*4 + 255)/256)*256;  // barrier uints
constexpr int BAR_N = NGRP*16 + 32;

typedef unsigned short ushortT;
typedef ushortT us8 __attribute__((ext_vector_type(8)));
typedef ushortT us4 __attribute__((ext_vector_type(4)));

__device__ __forceinline__ float bf2f(ushortT u) {
  return __uint_as_float(((unsigned)u) << 16);
}
__device__ __forceinline__ ushortT f2bf(float x) {
  __hip_bfloat16 h = __float2bfloat16(x);
  ushortT u; __builtin_memcpy(&u, &h, 2); return u;
}
__device__ __forceinline__ float sigf(float x) { return 1.0f / (1.0f + expf(-x)); }

__device__ __forceinline__ float red64(float v) {
  #pragma unroll
  for (int off = 32; off > 0; off >>= 1) v += __shfl_xor(v, off, 64);
  return v;
}

// K=1024 dot: bf16 row * fp32 vec; lane covers elems [lane*16, lane*16+16)
__device__ __forceinline__ float dot1024_bf(const ushortT* __restrict__ Wrow,
                                            const float* __restrict__ v, int lane) {
  const us8*    w8 = (const us8*)Wrow;
  const float4* v4 = (const float4*)v;
  float s = 0.f;
  #pragma unroll
  for (int c = 0; c < 2; ++c) {
    us8 w = w8[lane*2 + c];
    float4 a = v4[lane*4 + 2*c], b = v4[lane*4 + 2*c + 1];
    s += bf2f(w[0])*a.x + bf2f(w[1])*a.y + bf2f(w[2])*a.z + bf2f(w[3])*a.w
       + bf2f(w[4])*b.x + bf2f(w[5])*b.y + bf2f(w[6])*b.z + bf2f(w[7])*b.w;
  }
  return s;
}
// K=1024 dot: fp32 row * fp32 vec
__device__ __forceinline__ float dot1024_f(const float* __restrict__ Wrow,
                                           const float* __restrict__ v, int lane) {
  const float4* w4 = (const float4*)Wrow;
  const float4* v4 = (const float4*)v;
  float s = 0.f;
  #pragma unroll
  for (int c = 0; c < 4; ++c) {
    float4 w = w4[lane*4 + c], x = v4[lane*4 + c];
    s += w.x*x.x + w.y*x.y + w.z*x.z + w.w*x.w;
  }
  return s;
}

// two-level grid barrier (agent scope; release/acquire chain carries visibility)
__device__ __forceinline__ void gridbar(unsigned* bar, int bid) {
  __syncthreads();
  if (threadIdx.x == 0) {
    unsigned* grp  = bar + (bid / GRPSZ) * 16;
    unsigned* root = bar + NGRP * 16;
    unsigned* gen  = bar + NGRP * 16 + 16;
    unsigned g = __hip_atomic_load(gen, __ATOMIC_RELAXED, __HIP_MEMORY_SCOPE_AGENT);
    unsigned a = __hip_atomic_fetch_add(grp, 1u, __ATOMIC_ACQ_REL, __HIP_MEMORY_SCOPE_AGENT);
    bool done = false;
    if (a == GRPSZ - 1) {
      __hip_atomic_store(grp, 0u, __ATOMIC_RELAXED, __HIP_MEMORY_SCOPE_AGENT);
      unsigned r = __hip_atomic_fetch_add(root, 1u, __ATOMIC_ACQ_REL, __HIP_MEMORY_SCOPE_AGENT);
      if (r == NGRP - 1) {
        __hip_atomic_store(root, 0u, __ATOMIC_RELAXED, __HIP_MEMORY_SCOPE_AGENT);
        __hip_atomic_store(gen, g + 1u, __ATOMIC_RELEASE, __HIP_MEMORY_SCOPE_AGENT);
        done = true;
      }
    }
    if (!done) {
      while (__hip_atomic_load(gen, __ATOMIC_RELAXED, __HIP_MEMORY_SCOPE_AGENT) == g)
        __builtin_amdgcn_s_sleep(2);
      __builtin_amdgcn_fence(__ATOMIC_ACQUIRE, "agent");
    }
  }
  __syncthreads();
}

// ---------- prep kernels ----------
__global__ void conv_bf16(const float* __restrict__ src, ushortT* __restrict__ dst, size_t n) {
  size_t i  = blockIdx.x * (size_t)blockDim.x + threadIdx.x;
  size_t st = (size_t)gridDim.x * blockDim.x;
  for (; i < n; i += st) dst[i] = f2bf(src[i]);
}

__global__ void prep_kv(const float* __restrict__ text, const float* __restrict__ Wk,
                        const float* __restrict__ Wv, ushortT* __restrict__ keys,
                        ushortT* __restrict__ vals) {
  __shared__ float tx[ATT];
  const int t = blockIdx.x;
  for (int i = threadIdx.x; i < ATT; i += blockDim.x) tx[i] = text[(size_t)t*ATT + i];
  __syncthreads();
  for (int a = threadIdx.x; a < 2*ATT; a += blockDim.x) {
    const int which = (a >= ATT);
    const int ar = a - which*ATT;
    const float4* w4 = (const float4*)((which ? Wv : Wk) + (size_t)ar*ATT);
    const float4* t4 = (const float4*)tx;
    float s = 0.f;
    for (int i = 0; i < ATT/4; ++i) {
      float4 w = w4[i], x = t4[i];
      s += w.x*x.x + w.y*x.y + w.z*x.z + w.w*x.w;
    }
    (which ? vals : keys)[(size_t)t*ATT + ar] = f2bf(s);
  }
}

__global__ void prep_zero(float* f, unsigned* bar) {
  int i = blockIdx.x * blockDim.x + threadIdx.x;
  if (i < F_END) f[i] = 0.f;
  if (i < BAR_N) bar[i] = 0u;
}

// ---------- persistent AR kernel ----------
__global__ void __launch_bounds__(NT, 4)
ar_persist(const float* __restrict__ residual,
           const float* __restrict__ Whh0g, const float* __restrict__ Wih1g,
           const float* __restrict__ Whh1g,
           const float* __restrict__ b_a, const float* __restrict__ v_attn,
           const float* __restrict__ b0, const float* __restrict__ b1,
           const float* __restrict__ bd1, const float* __restrict__ bd2,
           const float* __restrict__ Wc, const float* __restrict__ bc,
           const float* __restrict__ Wg, const float* __restrict__ bg,
           float* __restrict__ out, void* __restrict__ wsraw)
{
  const int tid  = threadIdx.x;
  const int bid  = blockIdx.x;
  const int wid  = tid >> 6;     // 8 waves
  const int lane = tid & 63;

  const ushortT* uws = (const ushortT*)wsraw;
  float*    f   = (float*)((char*)wsraw + FBYTE);
  unsigned* bar = (unsigned*)((char*)wsraw + BBYTE);

  const ushortT* wq   = uws + O_WQ;
  const ushortT* wiha = uws + O_WIHA;
  const ushortT* whha = uws + O_WHHA;
  const ushortT* wih0 = uws + O_WIH0;
  const ushortT* wd1  = uws + O_WD1;
  const ushortT* wd2  = uws + O_WD2;
  const ushortT* keys = uws + O_KEYS;
  const ushortT* vals = uws + O_VALS;

  // this block: hidden units {2*bid, 2*bid+1}; wave wid -> gate gi of hidden hj
  const int hj = wid >> 2, gi = wid & 3;
  const int zrow = gi*H + bid*2 + hj;           // row of the 4H-dim z

  __shared__ ushortT lWhh0[8*H];   // 16 KB each
  __shared__ ushortT lWih1[8*H];
  __shared__ ushortT lWhh1[8*H];
  __shared__ float   lctx[ATT];
  __shared__ float   zl[8], zp[8], sc[32], cells[6], misc2[4];

  // ---- stage this block's rows into LDS (bf16) ----
  {
    const size_t rb = (size_t)zrow * H;
    for (int i = lane*4; i < H; i += 256) {
      float4 a = *(const float4*)(Whh0g + rb + i);
      us4 o = { f2bf(a.x), f2bf(a.y), f2bf(a.z), f2bf(a.w) };
      *(us4*)&lWhh0[wid*H + i] = o;
      a = *(const float4*)(Wih1g + rb + i);
      o = us4{ f2bf(a.x), f2bf(a.y), f2bf(a.z), f2bf(a.w) };
      *(us4*)&lWih1[wid*H + i] = o;
      a = *(const float4*)(Whh1g + rb + i);
      o = us4{ f2bf(a.x), f2bf(a.y), f2bf(a.z), f2bf(a.w) };
      *(us4*)&lWhh1[wid*H + i] = o;
    }
  }
  if (tid < 6) cells[tid] = 0.f;
  __syncthreads();

  int pa = 0, p1 = 0;

  for (int s = 0; s < T_STEPS; ++s) {
    // ===== P1: z_a = Wih_a@x + Whh_a@ha + b_a -> ha, ca =====
    {
      const float* x  = f + F_X;
      const float* ha = f + F_HA + pa*H;
      float s1 = 0.f;
      if (lane < 20) {
        us4 w = *(const us4*)(wiha + (size_t)zrow*NMEL + lane*4);
        float4 xv = *(const float4*)(x + lane*4);
        s1 = bf2f(w[0])*xv.x + bf2f(w[1])*xv.y + bf2f(w[2])*xv.z + bf2f(w[3])*xv.w;
      }
      s1 += dot1024_bf(whha + (size_t)zrow*H, ha, lane);
      s1 = red64(s1) + b_a[zrow];
      if (lane == 0) zl[wid] = s1;
    }
    __syncthreads();
    if (tid < 2) {
      float iv = zl[tid*4+0], fv = zl[tid*4+1], gv = zl[tid*4+2], ov = zl[tid*4+3];
      float c = sigf(fv)*cells[tid] + sigf(iv)*tanhf(gv);
      float h = sigf(ov)*tanhf(c);
      cells[tid] = c;
      f[F_HA + (pa^1)*H + bid*2 + tid] = h;
    }
    pa ^= 1;
    gridbar(bar, bid);

    // ===== P2: z0part = Wih0[:,:H]@ha + Whh0@h0 + b0 ; q rows ; gate_ha =====
    {
      const float* ha = f + F_HA + pa*H;
      const float* h0 = f + F_H0;
      float s2 = dot1024_bf(wih0 + (size_t)zrow*DIN, ha, lane)
               + dot1024_bf(lWhh0 + wid*H, h0, lane);
      s2 = red64(s2) + b0[zrow];
      if (lane == 0) zp[wid] = s2;
      if (wid == 0) {                       // q row bid
        float sq = dot1024_bf(wq + (size_t)bid*H, ha, lane);
        sq = red64(sq);
        if (lane == 0) f[F_Q + bid] = sq;
      }
      if (wid == 1 && bid < ATT - GBK) {    // q rows 512..639
        const int qr = GBK + bid;
        float sq = dot1024_bf(wq + (size_t)qr*H, ha, lane);
        sq = red64(sq);
        if (lane == 0) f[F_Q + qr] = sq;
      }
      if (bid == GBK-1 && wid == 2) {       // gate ha-part (fp32 Wg)
        float sg = dot1024_f(Wg, ha, lane);
        sg = red64(sg);
        if (lane == 0) misc2[0] = sg;
      }
    }
    gridbar(bar, bid);

    // ===== P3: attention partials (blocks 0..7 x 25 positions) =====
    if (bid < 8) {
      const float* q = f + F_Q;
      for (int pl = wid; pl < 25; pl += 8) {
        const int t = bid*25 + pl;
        float ss = 0.f;
        #pragma unroll
        for (int i = 0; i < 10; ++i) {
          const int idx = lane + 64*i;
          ss += tanhf(bf2f(keys[(size_t)t*ATT + idx]) + q[idx]) * v_attn[idx];
        }
        ss = red64(ss);
        if (lane == 0) sc[pl] = ss;
      }
      __syncthreads();
      if (tid == 0) {
        float m = sc[0];
        for (int i = 1; i < 25; ++i) m = fmaxf(m, sc[i]);
        misc2[1] = m;
      }
      __syncthreads();
      if (tid < 25) sc[tid] = expf(sc[tid] - misc2[1]);
      __syncthreads();
      if (tid == 0) {
        float z = 0.f;
        for (int i = 0; i < 25; ++i) z += sc[i];
        f[F_AM + bid] = misc2[1];
        f[F_AZ + bid] = z;
      }
      for (int a = tid; a < ATT; a += NT) {
        float acc = 0.f;
        for (int i = 0; i < 25; ++i)
          acc += sc[i] * bf2f(vals[(size_t)(bid*25 + i)*ATT + a]);
        f[F_CP + bid*ATT + a] = acc;
      }
    }
    gridbar(bar, bid);

    // ===== P4: ctx combine -> LDS ; z0 finish -> h0 ; gate out =====
    {
      float m = f[F_AM + 0];
      #pragma unroll
      for (int i = 1; i < 8; ++i) m = fmaxf(m, f[F_AM + i]);
      float wgt[8]; float Zt = 0.f;
      #pragma unroll
      for (int i = 0; i < 8; ++i) {
        wgt[i] = expf(f[F_AM + i] - m);
        Zt += wgt[i] * f[F_AZ + i];
      }
      const float inv = 1.0f / Zt;
      for (int a = tid; a < ATT; a += NT) {
        float c = 0.f;
        #pragma unroll
        for (int p = 0; p < 8; ++p) c += wgt[p] * f[F_CP + p*ATT + a];
        lctx[a] = c * inv;
      }
    }
    __syncthreads();
    {
      const ushortT* wr = wih0 + (size_t)zrow*DIN + H;
      float s4 = 0.f;
      #pragma unroll
      for (int i = 0; i < 10; ++i) {
        const int idx = lane + 64*i;
        s4 += bf2f(wr[idx]) * lctx[idx];
      }
      s4 = red64(s4) + zp[wid];
      if (lane == 0) zl[wid] = s4;
    }
    __syncthreads();
    if (tid < 2) {
      float iv = zl[tid*4+0], fv = zl[tid*4+1], gv = zl[tid*4+2], ov = zl[tid*4+3];
      float c = sigf(fv)*cells[2+tid] + sigf(iv)*tanhf(gv);
      float h = sigf(ov)*tanhf(c);
      cells[2+tid] = c;
      f[F_H0 + bid*2 + tid] = h;
    }
    if (bid == GBK-1 && wid == 3) {
      float sg = 0.f;
      #pragma unroll
      for (int i = 0; i < 10; ++i) {
        const int idx = lane + 64*i;
        sg += Wg[H + idx] * lctx[idx];
      }
      sg = red64(sg);
      if (lane == 0) out[T_STEPS*NMEL + s] = sigf(sg + misc2[0] + bg[0]);
    }
    gridbar(bar, bid);

    // ===== P5: z1 = Wih1@h0 + Whh1@h1 + b1 -> h1 (fully LDS) =====
    {
      const float* h0  = f + F_H0;
      const float* h1p = f + F_H1 + p1*H;
      float s5 = dot1024_bf(lWih1 + wid*H, h0, lane)
               + dot1024_bf(lWhh1 + wid*H, h1p, lane);
      s5 = red64(s5) + b1[zrow];
      if (lane == 0) zl[wid] = s5;
    }
    __syncthreads();
    if (tid < 2) {
      float iv = zl[tid*4+0], fv = zl[tid*4+1], gv = zl[tid*4+2], ov = zl[tid*4+3];
      float c = sigf(fv)*cells[4+tid] + sigf(iv)*tanhf(gv);
      float h = sigf(ov)*tanhf(c);
      cells[4+tid] = c;
      f[F_H1 + (p1^1)*H + bid*2 + tid] = h;
    }
    p1 ^= 1;
    gridbar(bar, bid);

    // ===== P6: d1 = tanh(Wd1@h1 + bd1) =====
    if (wid < 2) {
      const int r = bid*2 + wid;
      float s6 = dot1024_bf(wd1 + (size_t)r*H, f + F_H1 + p1*H, lane);
      s6 = red64(s6) + bd1[r];
      if (lane == 0) f[F_D1 + r] = tanhf(s6);
    }
    gridbar(bar, bid);

    // ===== P7: d = tanh(Wd2@d1 + bd2) =====
    if (wid < 2) {
      const int r = bid*2 + wid;
      float s7 = dot1024_bf(wd2 + (size_t)r*H, f + F_D1, lane);
      s7 = red64(s7) + bd2[r];
      if (lane == 0) f[F_D + r] = tanhf(s7);
    }
    gridbar(bar, bid);

    // ===== P8: dec_out rows (bid, 80+bid) ; out ; next x =====
    if (bid < NMEL) {
      if (wid < 2) {
        const int r = wid*NMEL + bid;   // wid0: log_s row, wid1: bb row
        float s8 = dot1024_f(Wc + (size_t)r*H, f + F_D, lane);
        s8 = red64(s8) + bc[r];
        if (lane == 0) misc2[2 + wid] = s8;
      }
      __syncthreads();
      if (tid == 0) {
        const int idx = T_STEPS - 1 - s;
        const float r = residual[idx*NMEL + bid];
        const float o = (r - misc2[3]) * expf(-misc2[2]);
        out[idx*NMEL + bid] = o;
        f[F_X + bid] = o;
      }
    }
    gridbar(bar, bid);
  }
}

extern "C" void kernel_launch(void* const* d_in, const int* in_sizes, int n_in,
                              void* d_out, int out_size, void* d_ws, size_t ws_size,
                              hipStream_t stream) {
  const float* residual = (const float*)d_in[0];
  const float* text   = (const float*)d_in[1];
  const float* Wih_a  = (const float*)d_in[2];
  const float* Whh_a  = (const float*)d_in[3];
  const float* b_a    = (const float*)d_in[4];
  const float* Wq     = (const float*)d_in[5];
  const float* Wk     = (const float*)d_in[6];
  const float* Wv     = (const float*)d_in[7];
  const float* v_attn = (const float*)d_in[8];
  const float* Wih0   = (const float*)d_in[9];
  const float* Whh0   = (const float*)d_in[10];
  const float* b0     = (const float*)d_in[11];
  const float* Wih1   = (const float*)d_in[12];
  const float* Whh1   = (const float*)d_in[13];
  const float* b1     = (const float*)d_in[14];
  const float* Wd1    = (const float*)d_in[15];
  const float* bd1    = (const float*)d_in[16];
  const float* Wd2    = (const float*)d_in[17];
  const float* bd2    = (const float*)d_in[18];
  const float* Wc     = (const float*)d_in[19];
  const float* bc     = (const float*)d_in[20];
  const float* Wg     = (const float*)d_in[21];
  const float* bg     = (const float*)d_in[22];
  float* out = (float*)d_out;

  char* wsb = (char*)d_ws;
  ushortT*  u   = (ushortT*)wsb;
  float*    f   = (float*)(wsb + FBYTE);
  unsigned* bar = (unsigned*)(wsb + BBYTE);

  // bf16 weight conversions into ws
  conv_bf16<<<1024, 256, 0, stream>>>(Wq,    u + O_WQ,   (size_t)ATT*H);
  conv_bf16<<<1024, 256, 0, stream>>>(Wih_a, u + O_WIHA, (size_t)4*H*NMEL);
  conv_bf16<<<1024, 256, 0, stream>>>(Whh_a, u + O_WHHA, (size_t)4*H*H);
  conv_bf16<<<1024, 256, 0, stream>>>(Wih0,  u + O_WIH0, (size_t)4*H*DIN);
  conv_bf16<<<1024, 256, 0, stream>>>(Wd1,   u + O_WD1,  (size_t)H*H);
  conv_bf16<<<1024, 256, 0, stream>>>(Wd2,   u + O_WD2,  (size_t)H*H);
  prep_kv<<<TXT, 256, 0, stream>>>(text, Wk, Wv, u + O_KEYS, u + O_VALS);
  prep_zero<<<(F_END + 255)/256, 256, 0, stream>>>(f, bar);

  ar_persist<<<GBK, NT, 0, stream>>>(residual, Whh0, Wih1, Whh1,
      b_a, v_attn, b0, b1, bd1, bd2, Wc, bc, Wg, bg, out, d_ws);
}

// Round 4
// 59832.501 us; speedup vs baseline: 2.3225x; 1.7353x over previous
//
#include <hip/hip_runtime.h>
#include <hip/hip_bf16.h>
#include <math.h>

#define GBK 512          // grid blocks (2 per CU, co-resident)
#define NT  512          // threads per block (8 waves)

constexpr int T_STEPS = 600;
constexpr int TXT     = 200;
constexpr int NMEL    = 80;
constexpr int H       = 1024;
constexpr int ATT     = 640;
constexpr int DIN     = H + ATT;   // 1664
constexpr int NGRP    = 16;        // barrier groups
constexpr int GRPSZ   = GBK / NGRP;

// ---- ws layout: bf16 region (ushort element offsets) ----
constexpr size_t O_WQ    = 0;                                  // 640*1024
constexpr size_t O_WIHA  = O_WQ   + (size_t)ATT*H;             // 4096*80
constexpr size_t O_WHHA  = O_WIHA + (size_t)4*H*NMEL;          // 4096*1024
constexpr size_t O_WIH0  = O_WHHA + (size_t)4*H*H;             // 4096*1664
constexpr size_t O_WD1   = O_WIH0 + (size_t)4*H*DIN;           // 1024*1024
constexpr size_t O_WD2   = O_WD1  + (size_t)H*H;
constexpr size_t O_KEYS  = O_WD2  + (size_t)H*H;               // 200*640
constexpr size_t O_VALS  = O_KEYS + (size_t)TXT*ATT;
constexpr size_t O_END_U = O_VALS + (size_t)TXT*ATT;
constexpr size_t FBYTE   = ((O_END_U*2 + 255)/256)*256;        // float region start (bytes)
// ---- float region (float element offsets) ----
constexpr int F_X  = 0;            // 128 (80 used)
constexpr int F_HA = 128;          // 2*H ping-pong
constexpr int F_H0 = F_HA + 2*H;   // H
constexpr int F_H1 = F_H0 + H;     // 2*H ping-pong
constexpr int F_Q  = F_H1 + 2*H;   // ATT
constexpr int F_D1 = F_Q  + ATT;   // H
constexpr int F_D  = F_D1 + H;     // H
constexpr int F_AM = F_D  + H;     // 8
constexpr int F_AZ = F_AM + 8;     // 8  (contiguous after F_AM)
constexpr int F_CP = F_AZ + 8;     // 8*ATT
constexpr int F_END= F_CP + 8*ATT;
constexpr size_t BBYTE  = FBYTE + (((size_t)F_END*4 + 255)/256)*256;  // barrier uints
// barrier layout (uint idx, 64-uint = 256B stride per line):
//   grp_cnt[g] @ g*64 ; root @ NGRP*64 ; gen_global @ (NGRP+1)*64 ; grp_gen[g] @ (NGRP+2+g)*64
constexpr int BAR_N = (2*NGRP + 2) * 64;   // 2176 uints

typedef unsigned short ushortT;
typedef ushortT us8 __attribute__((ext_vector_type(8)));
typedef ushortT us4 __attribute__((ext_vector_type(4)));

__device__ __forceinline__ float bf2f(ushortT u) {
  return __uint_as_float(((unsigned)u) << 16);
}
__device__ __forceinline__ ushortT f2bf(float x) {
  __hip_bfloat16 h = __float2bfloat16(x);
  ushortT u; __builtin_memcpy(&u, &h, 2); return u;
}
__device__ __forceinline__ float sigf(float x) { return 1.0f / (1.0f + expf(-x)); }

__device__ __forceinline__ float red64(float v) {
  #pragma unroll
  for (int off = 32; off > 0; off >>= 1) v += __shfl_xor(v, off, 64);
  return v;
}

// coherent (agent-scope, cache-bypassing) accessors for dynamic cross-block data
__device__ __forceinline__ float cload(const float* p) {
  return __hip_atomic_load(p, __ATOMIC_RELAXED, __HIP_MEMORY_SCOPE_AGENT);
}
__device__ __forceinline__ void cstore(float* p, float v) {
  __hip_atomic_store(p, v, __ATOMIC_RELAXED, __HIP_MEMORY_SCOPE_AGENT);
}
__device__ __forceinline__ void cstage(float* dst, const float* src, int n) {
  for (int i = threadIdx.x; i < n; i += NT) dst[i] = cload(src + i);
}

// K=1024 dot: bf16 row * fp32 vec (LDS); lane covers elems [lane*16, lane*16+16)
__device__ __forceinline__ float dot1024_bf(const ushortT* __restrict__ Wrow,
                                            const float* __restrict__ v, int lane) {
  const us8*    w8 = (const us8*)Wrow;
  const float4* v4 = (const float4*)v;
  float s = 0.f;
  #pragma unroll
  for (int c = 0; c < 2; ++c) {
    us8 w = w8[lane*2 + c];
    float4 a = v4[lane*4 + 2*c], b = v4[lane*4 + 2*c + 1];
    s += bf2f(w[0])*a.x + bf2f(w[1])*a.y + bf2f(w[2])*a.z + bf2f(w[3])*a.w
       + bf2f(w[4])*b.x + bf2f(w[5])*b.y + bf2f(w[6])*b.z + bf2f(w[7])*b.w;
  }
  return s;
}
// K=1024 dot: fp32 row * fp32 vec (LDS)
__device__ __forceinline__ float dot1024_f(const float* __restrict__ Wrow,
                                           const float* __restrict__ v, int lane) {
  const float4* w4 = (const float4*)Wrow;
  const float4* v4 = (const float4*)v;
  float s = 0.f;
  #pragma unroll
  for (int c = 0; c < 4; ++c) {
    float4 w = w4[lane*4 + c], x = v4[lane*4 + c];
    s += w.x*x.x + w.y*x.y + w.z*x.z + w.w*x.w;
  }
  return s;
}

__device__ __forceinline__ unsigned aload(unsigned* p) {
  return __hip_atomic_load(p, __ATOMIC_RELAXED, __HIP_MEMORY_SCOPE_AGENT);
}

// hierarchical grid barrier, monotonic counters, hierarchical wakeup,
// NO acquire fences (data moves via coherent atomic load/store).
__device__ __forceinline__ void gridbar(unsigned* bar, int bid, unsigned n) {
  __syncthreads();
  if (threadIdx.x == 0) {
    const int g = bid / GRPSZ;
    unsigned* gcnt = bar + g * 64;
    unsigned* root = bar + NGRP * 64;
    unsigned* ggen = bar + (NGRP + 1) * 64;
    unsigned* lgen = bar + (NGRP + 2 + g) * 64;
    __builtin_amdgcn_fence(__ATOMIC_RELEASE, "agent");   // drain my stores to coherence point
    unsigned a = __hip_atomic_fetch_add(gcnt, 1u, __ATOMIC_RELAXED, __HIP_MEMORY_SCOPE_AGENT);
    if (a == n * GRPSZ - 1) {                  // last of group -> leader
      unsigned r = __hip_atomic_fetch_add(root, 1u, __ATOMIC_RELAXED, __HIP_MEMORY_SCOPE_AGENT);
      if (r == n * NGRP - 1) {                 // last leader -> releaser
        __hip_atomic_store(ggen, n, __ATOMIC_RELAXED, __HIP_MEMORY_SCOPE_AGENT);
      } else {
        while (aload(ggen) < n) __builtin_amdgcn_s_sleep(1);
      }
      __hip_atomic_store(lgen, n, __ATOMIC_RELAXED, __HIP_MEMORY_SCOPE_AGENT);
    } else {
      while (aload(lgen) < n) __builtin_amdgcn_s_sleep(2);
    }
  }
  __syncthreads();
}

// ---------- prep kernels ----------
__global__ void conv_bf16(const float* __restrict__ src, ushortT* __restrict__ dst, size_t n) {
  size_t i  = blockIdx.x * (size_t)blockDim.x + threadIdx.x;
  size_t st = (size_t)gridDim.x * blockDim.x;
  for (; i < n; i += st) dst[i] = f2bf(src[i]);
}

__global__ void prep_kv(const float* __restrict__ text, const float* __restrict__ Wk,
                        const float* __restrict__ Wv, ushortT* __restrict__ keys,
                        ushortT* __restrict__ vals) {
  __shared__ float tx[ATT];
  const int t = blockIdx.x;
  for (int i = threadIdx.x; i < ATT; i += blockDim.x) tx[i] = text[(size_t)t*ATT + i];
  __syncthreads();
  for (int a = threadIdx.x; a < 2*ATT; a += blockDim.x) {
    const int which = (a >= ATT);
    const int ar = a - which*ATT;
    const float4* w4 = (const float4*)((which ? Wv : Wk) + (size_t)ar*ATT);
    const float4* t4 = (const float4*)tx;
    float s = 0.f;
    for (int i = 0; i < ATT/4; ++i) {
      float4 w = w4[i], x = t4[i];
      s += w.x*x.x + w.y*x.y + w.z*x.z + w.w*x.w;
    }
    (which ? vals : keys)[(size_t)t*ATT + ar] = f2bf(s);
  }
}

__global__ void prep_zero(float* f, unsigned* bar) {
  int i = blockIdx.x * blockDim.x + threadIdx.x;
  if (i < F_END) f[i] = 0.f;
  if (i < BAR_N) bar[i] = 0u;
}

// ---------- persistent AR kernel ----------
__global__ void __launch_bounds__(NT, 4)
ar_persist(const float* __restrict__ residual,
           const float* __restrict__ Whh0g, const float* __restrict__ Wih1g,
           const float* __restrict__ Whh1g,
           const float* __restrict__ b_a, const float* __restrict__ v_attn,
           const float* __restrict__ b0, const float* __restrict__ b1,
           const float* __restrict__ bd1, const float* __restrict__ bd2,
           const float* __restrict__ Wc, const float* __restrict__ bc,
           const float* __restrict__ Wg, const float* __restrict__ bg,
           float* __restrict__ out, void* __restrict__ wsraw)
{
  const int tid  = threadIdx.x;
  const int bid  = blockIdx.x;
  const int wid  = tid >> 6;     // 8 waves
  const int lane = tid & 63;

  const ushortT* uws = (const ushortT*)wsraw;
  float*    f   = (float*)((char*)wsraw + FBYTE);
  unsigned* bar = (unsigned*)((char*)wsraw + BBYTE);

  const ushortT* wq   = uws + O_WQ;
  const ushortT* wiha = uws + O_WIHA;
  const ushortT* whha = uws + O_WHHA;
  const ushortT* wih0 = uws + O_WIH0;
  const ushortT* wd1  = uws + O_WD1;
  const ushortT* wd2  = uws + O_WD2;
  const ushortT* keys = uws + O_KEYS;
  const ushortT* vals = uws + O_VALS;

  // this block: hidden units {2*bid, 2*bid+1}; wave wid -> gate gi of hidden hj
  const int hj = wid >> 2, gi = wid & 3;
  const int zrow = gi*H + bid*2 + hj;           // row of the 4H-dim z

  __shared__ ushortT lWhh0[8*H];   // 16 KB each
  __shared__ ushortT lWih1[8*H];
  __shared__ ushortT lWhh1[8*H];
  __shared__ float   lctx[ATT];    // q (P3) / ctx (P4)
  __shared__ float   shv[2048];
  __shared__ float   zl[8], zp[8], sc[32], cells[6], misc2[4], sAMZ[16];

  // ---- stage this block's rows into LDS (bf16, cached reads — before any fence) ----
  {
    const size_t rb = (size_t)zrow * H;
    for (int i = lane*4; i < H; i += 256) {
      float4 a = *(const float4*)(Whh0g + rb + i);
      us4 o = { f2bf(a.x), f2bf(a.y), f2bf(a.z), f2bf(a.w) };
      *(us4*)&lWhh0[wid*H + i] = o;
      a = *(const float4*)(Wih1g + rb + i);
      o = us4{ f2bf(a.x), f2bf(a.y), f2bf(a.z), f2bf(a.w) };
      *(us4*)&lWih1[wid*H + i] = o;
      a = *(const float4*)(Whh1g + rb + i);
      o = us4{ f2bf(a.x), f2bf(a.y), f2bf(a.z), f2bf(a.w) };
      *(us4*)&lWhh1[wid*H + i] = o;
    }
  }
  if (tid < 6) cells[tid] = 0.f;
  __syncthreads();

  int pa = 0, p1 = 0;
  unsigned nb = 0;   // barrier index (monotonic)

  for (int s = 0; s < T_STEPS; ++s) {
    // ===== P1: z_a = Wih_a@x + Whh_a@ha + b_a -> ha, ca =====
    cstage(shv, f + F_X, 80);
    cstage(shv + 128, f + F_HA + pa*H, H);
    __syncthreads();
    {
      float s1 = 0.f;
      if (lane < 20) {
        us4 w = *(const us4*)(wiha + (size_t)zrow*NMEL + lane*4);
        float4 xv = *(const float4*)(shv + lane*4);
        s1 = bf2f(w[0])*xv.x + bf2f(w[1])*xv.y + bf2f(w[2])*xv.z + bf2f(w[3])*xv.w;
      }
      s1 += dot1024_bf(whha + (size_t)zrow*H, shv + 128, lane);
      s1 = red64(s1) + b_a[zrow];
      if (lane == 0) zl[wid] = s1;
    }
    __syncthreads();
    if (tid < 2) {
      float iv = zl[tid*4+0], fv = zl[tid*4+1], gv = zl[tid*4+2], ov = zl[tid*4+3];
      float c = sigf(fv)*cells[tid] + sigf(iv)*tanhf(gv);
      float h = sigf(ov)*tanhf(c);
      cells[tid] = c;
      cstore(f + F_HA + (pa^1)*H + bid*2 + tid, h);
    }
    pa ^= 1;
    gridbar(bar, bid, ++nb);

    // ===== P2: z0part = Wih0[:,:H]@ha + Whh0@h0 + b0 ; q rows ; gate_ha =====
    cstage(shv, f + F_HA + pa*H, H);
    cstage(shv + 1024, f + F_H0, H);
    __syncthreads();
    {
      float s2 = dot1024_bf(wih0 + (size_t)zrow*DIN, shv, lane)
               + dot1024_bf(lWhh0 + wid*H, shv + 1024, lane);
      s2 = red64(s2) + b0[zrow];
      if (lane == 0) zp[wid] = s2;
      if (wid == 0) {                       // q row bid
        float sq = dot1024_bf(wq + (size_t)bid*H, shv, lane);
        sq = red64(sq);
        if (lane == 0) cstore(f + F_Q + bid, sq);
      }
      if (wid == 1 && bid < ATT - GBK) {    // q rows 512..639
        const int qr = GBK + bid;
        float sq = dot1024_bf(wq + (size_t)qr*H, shv, lane);
        sq = red64(sq);
        if (lane == 0) cstore(f + F_Q + qr, sq);
      }
      if (bid == GBK-1 && wid == 2) {       // gate ha-part (fp32 Wg)
        float sg = dot1024_f(Wg, shv, lane);
        sg = red64(sg);
        if (lane == 0) misc2[0] = sg;
      }
    }
    gridbar(bar, bid, ++nb);

    // ===== P3: attention partials (blocks 0..7 x 25 positions) =====
    if (bid < 8) {
      cstage(lctx, f + F_Q, ATT);
      __syncthreads();
      for (int pl = wid; pl < 25; pl += 8) {
        const int t = bid*25 + pl;
        float ss = 0.f;
        #pragma unroll
        for (int i = 0; i < 10; ++i) {
          const int idx = lane + 64*i;
          ss += tanhf(bf2f(keys[(size_t)t*ATT + idx]) + lctx[idx]) * v_attn[idx];
        }
        ss = red64(ss);
        if (lane == 0) sc[pl] = ss;
      }
      __syncthreads();
      if (tid == 0) {
        float m = sc[0];
        for (int i = 1; i < 25; ++i) m = fmaxf(m, sc[i]);
        misc2[1] = m;
      }
      __syncthreads();
      if (tid < 25) sc[tid] = expf(sc[tid] - misc2[1]);
      __syncthreads();
      if (tid == 0) {
        float z = 0.f;
        for (int i = 0; i < 25; ++i) z += sc[i];
        cstore(f + F_AM + bid, misc2[1]);
        cstore(f + F_AZ + bid, z);
      }
      for (int a = tid; a < ATT; a += NT) {
        float acc = 0.f;
        for (int i = 0; i < 25; ++i)
          acc += sc[i] * bf2f(vals[(size_t)(bid*25 + i)*ATT + a]);
        cstore(f + F_CP + bid*ATT + a, acc);
      }
    }
    gridbar(bar, bid, ++nb);

    // ===== P4: ctx combine -> LDS ; z0 finish -> h0 ; gate out =====
    if (tid < 16) sAMZ[tid] = cload(f + F_AM + tid);   // 8 max + 8 sum (contiguous)
    __syncthreads();
    {
      float m = sAMZ[0];
      #pragma unroll
      for (int i = 1; i < 8; ++i) m = fmaxf(m, sAMZ[i]);
      float wgt[8]; float Zt = 0.f;
      #pragma unroll
      for (int i = 0; i < 8; ++i) {
        wgt[i] = expf(sAMZ[i] - m);
        Zt += wgt[i] * sAMZ[8 + i];
      }
      const float inv = 1.0f / Zt;
      for (int a = tid; a < ATT; a += NT) {
        float c = 0.f;
        #pragma unroll
        for (int p = 0; p < 8; ++p) c += wgt[p] * cload(f + F_CP + p*ATT + a);
        lctx[a] = c * inv;
      }
    }
    __syncthreads();
    {
      const ushortT* wr = wih0 + (size_t)zrow*DIN + H;
      float s4 = 0.f;
      #pragma unroll
      for (int i = 0; i < 10; ++i) {
        const int idx = lane + 64*i;
        s4 += bf2f(wr[idx]) * lctx[idx];
      }
      s4 = red64(s4) + zp[wid];
      if (lane == 0) zl[wid] = s4;
    }
    __syncthreads();
    if (tid < 2) {
      float iv = zl[tid*4+0], fv = zl[tid*4+1], gv = zl[tid*4+2], ov = zl[tid*4+3];
      float c = sigf(fv)*cells[2+tid] + sigf(iv)*tanhf(gv);
      float h = sigf(ov)*tanhf(c);
      cells[2+tid] = c;
      cstore(f + F_H0 + bid*2 + tid, h);
    }
    if (bid == GBK-1 && wid == 3) {
      float sg = 0.f;
      #pragma unroll
      for (int i = 0; i < 10; ++i) {
        const int idx = lane + 64*i;
        sg += Wg[H + idx] * lctx[idx];
      }
      sg = red64(sg);
      if (lane == 0) out[T_STEPS*NMEL + s] = sigf(sg + misc2[0] + bg[0]);
    }
    gridbar(bar, bid, ++nb);

    // ===== P5: z1 = Wih1@h0 + Whh1@h1 + b1 -> h1 (weights in LDS) =====
    cstage(shv, f + F_H0, H);
    cstage(shv + 1024, f + F_H1 + p1*H, H);
    __syncthreads();
    {
      float s5 = dot1024_bf(lWih1 + wid*H, shv, lane)
               + dot1024_bf(lWhh1 + wid*H, shv + 1024, lane);
      s5 = red64(s5) + b1[zrow];
      if (lane == 0) zl[wid] = s5;
    }
    __syncthreads();
    if (tid < 2) {
      float iv = zl[tid*4+0], fv = zl[tid*4+1], gv = zl[tid*4+2], ov = zl[tid*4+3];
      float c = sigf(fv)*cells[4+tid] + sigf(iv)*tanhf(gv);
      float h = sigf(ov)*tanhf(c);
      cells[4+tid] = c;
      cstore(f + F_H1 + (p1^1)*H + bid*2 + tid, h);
    }
    p1 ^= 1;
    gridbar(bar, bid, ++nb);

    // ===== P6: d1 = tanh(Wd1@h1 + bd1) =====
    cstage(shv, f + F_H1 + p1*H, H);
    __syncthreads();
    if (wid < 2) {
      const int r = bid*2 + wid;
      float s6 = dot1024_bf(wd1 + (size_t)r*H, shv, lane);
      s6 = red64(s6) + bd1[r];
      if (lane == 0) cstore(f + F_D1 + r, tanhf(s6));
    }
    gridbar(bar, bid, ++nb);

    // ===== P7: d = tanh(Wd2@d1 + bd2) =====
    cstage(shv, f + F_D1, H);
    __syncthreads();
    if (wid < 2) {
      const int r = bid*2 + wid;
      float s7 = dot1024_bf(wd2 + (size_t)r*H, shv, lane);
      s7 = red64(s7) + bd2[r];
      if (lane == 0) cstore(f + F_D + r, tanhf(s7));
    }
    gridbar(bar, bid, ++nb);

    // ===== P8: dec_out rows (bid, 80+bid) ; out ; next x =====
    if (bid < NMEL) {
      cstage(shv, f + F_D, H);
      __syncthreads();
      if (wid < 2) {
        const int r = wid*NMEL + bid;   // wid0: log_s row, wid1: bb row
        float s8 = dot1024_f(Wc + (size_t)r*H, shv, lane);
        s8 = red64(s8) + bc[r];
        if (lane == 0) misc2[2 + wid] = s8;
      }
      __syncthreads();
      if (tid == 0) {
        const int idx = T_STEPS - 1 - s;
        const float r = residual[idx*NMEL + bid];
        const float o = (r - misc2[3]) * expf(-misc2[2]);
        out[idx*NMEL + bid] = o;
        cstore(f + F_X + bid, o);
      }
    }
    gridbar(bar, bid, ++nb);
  }
}

extern "C" void kernel_launch(void* const* d_in, const int* in_sizes, int n_in,
                              void* d_out, int out_size, void* d_ws, size_t ws_size,
                              hipStream_t stream) {
  const float* residual = (const float*)d_in[0];
  const float* text   = (const float*)d_in[1];
  const float* Wih_a  = (const float*)d_in[2];
  const float* Whh_a  = (const float*)d_in[3];
  const float* b_a    = (const float*)d_in[4];
  const float* Wq     = (const float*)d_in[5];
  const float* Wk     = (const float*)d_in[6];
  const float* Wv     = (const float*)d_in[7];
  const float* v_attn = (const float*)d_in[8];
  const float* Wih0   = (const float*)d_in[9];
  const float* Whh0   = (const float*)d_in[10];
  const float* b0     = (const float*)d_in[11];
  const float* Wih1   = (const float*)d_in[12];
  const float* Whh1   = (const float*)d_in[13];
  const float* b1     = (const float*)d_in[14];
  const float* Wd1    = (const float*)d_in[15];
  const float* bd1    = (const float*)d_in[16];
  const float* Wd2    = (const float*)d_in[17];
  const float* bd2    = (const float*)d_in[18];
  const float* Wc     = (const float*)d_in[19];
  const float* bc     = (const float*)d_in[20];
  const float* Wg     = (const float*)d_in[21];
  const float* bg     = (const float*)d_in[22];
  float* out = (float*)d_out;

  char* wsb = (char*)d_ws;
  ushortT*  u   = (ushortT*)wsb;
  float*    f   = (float*)(wsb + FBYTE);
  unsigned* bar = (unsigned*)(wsb + BBYTE);

  // bf16 weight conversions into ws
  conv_bf16<<<1024, 256, 0, stream>>>(Wq,    u + O_WQ,   (size_t)ATT*H);
  conv_bf16<<<1024, 256, 0, stream>>>(Wih_a, u + O_WIHA, (size_t)4*H*NMEL);
  conv_bf16<<<1024, 256, 0, stream>>>(Whh_a, u + O_WHHA, (size_t)4*H*H);
  conv_bf16<<<1024, 256, 0, stream>>>(Wih0,  u + O_WIH0, (size_t)4*H*DIN);
  conv_bf16<<<1024, 256, 0, stream>>>(Wd1,   u + O_WD1,  (size_t)H*H);
  conv_bf16<<<1024, 256, 0, stream>>>(Wd2,   u + O_WD2,  (size_t)H*H);
  prep_kv<<<TXT, 256, 0, stream>>>(text, Wk, Wv, u + O_KEYS, u + O_VALS);
  prep_zero<<<(F_END + 255)/256, 256, 0, stream>>>(f, bar);

  ar_persist<<<GBK, NT, 0, stream>>>(residual, Whh0, Wih1, Whh1,
      b_a, v_attn, b0, b1, bd1, bd2, Wc, bc, Wg, bg, out, d_ws);
}

// Round 5
// 45771.445 us; speedup vs baseline: 3.0359x; 1.3072x over previous
//
#include <hip/hip_runtime.h>
#include <hip/hip_bf16.h>
#include <math.h>

#define GBK 512          // grid blocks (2 per CU, co-resident)
#define NT  512          // threads per block (8 waves)

constexpr int T_STEPS = 600;
constexpr int TXT     = 200;
constexpr int NMEL    = 80;
constexpr int H       = 1024;
constexpr int ATT     = 640;
constexpr int DIN     = H + ATT;   // 1664
constexpr int NGRP    = 16;        // wakeup relay groups
constexpr int GRPSZ   = GBK / NGRP;
constexpr int GATE_B  = 500;       // block computing the gate output

// ---- ws layout: bf16 region (ushort element offsets) ----
constexpr size_t O_WQ    = 0;                                  // 640*1024
constexpr size_t O_WIHA  = O_WQ   + (size_t)ATT*H;             // 4096*80
constexpr size_t O_WIH0  = O_WIHA + (size_t)4*H*NMEL;          // 4096*1664
constexpr size_t O_WHH1  = O_WIH0 + (size_t)4*H*DIN;           // 4096*1024
constexpr size_t O_WD1   = O_WHH1 + (size_t)4*H*H;             // 1024*1024
constexpr size_t O_WD2   = O_WD1  + (size_t)H*H;
constexpr size_t O_KEYS  = O_WD2  + (size_t)H*H;               // 200*640
constexpr size_t O_VALS  = O_KEYS + (size_t)TXT*ATT;
constexpr size_t O_END_U = O_VALS + (size_t)TXT*ATT;
constexpr size_t FBYTE   = ((O_END_U*2 + 255)/256)*256;        // float region start (bytes)
// ---- float region (float element offsets) ----
constexpr int F_X  = 0;            // 128 (80 used)
constexpr int F_HA = 128;          // 2*H ping-pong
constexpr int F_H0 = F_HA + 2*H;   // H
constexpr int F_H1 = F_H0 + H;     // 2*H ping-pong
constexpr int F_Q  = F_H1 + 2*H;   // ATT
constexpr int F_D1 = F_Q  + ATT;   // H
constexpr int F_D  = F_D1 + H;     // H
constexpr int F_AM = F_D  + H;     // 8
constexpr int F_AZ = F_AM + 8;     // 8 (contiguous after F_AM)
constexpr int F_CP = F_AZ + 8;     // 8*ATT
constexpr int F_END= F_CP + 8*ATT;
constexpr size_t BBYTE  = FBYTE + (((size_t)F_END*4 + 255)/256)*256;
// barrier region (uint offsets): per-block flags (16B stride), ggen line, lgen lines
constexpr int BAR_GGEN = GBK*4;
constexpr int BAR_LGEN = GBK*4 + 64;
constexpr int BAR_N    = GBK*4 + 64 + NGRP*64;

typedef unsigned short ushortT;
typedef ushortT us4 __attribute__((ext_vector_type(4)));

__device__ __forceinline__ float bf2f(ushortT u) {
  return __uint_as_float(((unsigned)u) << 16);
}
__device__ __forceinline__ ushortT f2bf(float x) {
  __hip_bfloat16 h = __float2bfloat16(x);
  ushortT u; __builtin_memcpy(&u, &h, 2); return u;
}
__device__ __forceinline__ us4 cvt4(float4 a) {
  return us4{ f2bf(a.x), f2bf(a.y), f2bf(a.z), f2bf(a.w) };
}
__device__ __forceinline__ float sigf(float x) { return 1.0f / (1.0f + expf(-x)); }

__device__ __forceinline__ float red64(float v) {
  #pragma unroll
  for (int off = 32; off > 0; off >>= 1) v += __shfl_xor(v, off, 64);
  return v;
}

// coherent (agent-scope, cache-bypassing) accessors for dynamic cross-block data
__device__ __forceinline__ float cload(const float* p) {
  return __hip_atomic_load(p, __ATOMIC_RELAXED, __HIP_MEMORY_SCOPE_AGENT);
}
__device__ __forceinline__ void cstore(float* p, float v) {
  __hip_atomic_store(p, v, __ATOMIC_RELAXED, __HIP_MEMORY_SCOPE_AGENT);
}
__device__ __forceinline__ void cstage(float* dst, const float* src, int n) {
  for (int i = threadIdx.x; i < n; i += NT) dst[i] = cload(src + i);
}
__device__ __forceinline__ unsigned aload(const unsigned* p) {
  return __hip_atomic_load(p, __ATOMIC_RELAXED, __HIP_MEMORY_SCOPE_AGENT);
}
__device__ __forceinline__ void astore(unsigned* p, unsigned v) {
  __hip_atomic_store(p, v, __ATOMIC_RELAXED, __HIP_MEMORY_SCOPE_AGENT);
}

// ---- conflict-free dots: lane handles elems {c*256 + lane*4 .. +4} ----
// K=1024, bf16 row (LDS or global) * fp32 vec (LDS)
__device__ __forceinline__ float dotbf(const ushortT* __restrict__ Wrow,
                                       const float* __restrict__ v, int lane) {
  const us4* w4 = (const us4*)Wrow;
  const float4* v4 = (const float4*)v;
  float s = 0.f;
  #pragma unroll
  for (int c = 0; c < 4; ++c) {
    us4 w = w4[c*64 + lane];
    float4 x = v4[c*64 + lane];
    s += bf2f(w[0])*x.x + bf2f(w[1])*x.y + bf2f(w[2])*x.z + bf2f(w[3])*x.w;
  }
  return s;
}
// K=640, bf16 row * fp32 vec
__device__ __forceinline__ float dot640bf(const ushortT* __restrict__ Wrow,
                                          const float* __restrict__ v, int lane) {
  const us4* w4 = (const us4*)Wrow;
  const float4* v4 = (const float4*)v;
  float s = 0.f;
  #pragma unroll
  for (int c = 0; c < 2; ++c) {
    us4 w = w4[c*64 + lane];
    float4 x = v4[c*64 + lane];
    s += bf2f(w[0])*x.x + bf2f(w[1])*x.y + bf2f(w[2])*x.z + bf2f(w[3])*x.w;
  }
  if (lane < 32) {
    us4 w = w4[128 + lane];
    float4 x = v4[128 + lane];
    s += bf2f(w[0])*x.x + bf2f(w[1])*x.y + bf2f(w[2])*x.z + bf2f(w[3])*x.w;
  }
  return s;
}
// K=1024, fp32 row * fp32 vec
__device__ __forceinline__ float dotf(const float* __restrict__ Wrow,
                                      const float* __restrict__ v, int lane) {
  const float4* w4 = (const float4*)Wrow;
  const float4* v4 = (const float4*)v;
  float s = 0.f;
  #pragma unroll
  for (int c = 0; c < 4; ++c) {
    float4 w = w4[c*64 + lane], x = v4[c*64 + lane];
    s += w.x*x.x + w.y*x.y + w.z*x.z + w.w*x.w;
  }
  return s;
}
// K=640, fp32 row * fp32 vec
__device__ __forceinline__ float dot640f(const float* __restrict__ Wrow,
                                         const float* __restrict__ v, int lane) {
  const float4* w4 = (const float4*)Wrow;
  const float4* v4 = (const float4*)v;
  float s = 0.f;
  #pragma unroll
  for (int c = 0; c < 2; ++c) {
    float4 w = w4[c*64 + lane], x = v4[c*64 + lane];
    s += w.x*x.x + w.y*x.y + w.z*x.z + w.w*x.w;
  }
  if (lane < 32) {
    float4 w = w4[128 + lane], x = v4[128 + lane];
    s += w.x*x.x + w.y*x.y + w.z*x.z + w.w*x.w;
  }
  return s;
}

// flag-based grid barrier: parallel arrival detection by block GBK-1,
// monotonic epochs, relay-tree wakeup, no acquire fences (data via cload/cstore).
__device__ __forceinline__ void gridbar(unsigned* bar, int bid, unsigned n) {
  __syncthreads();
  const int tid = threadIdx.x;
  if (bid == GBK - 1) {
    if (tid == 0) __builtin_amdgcn_fence(__ATOMIC_RELEASE, "agent");
    __syncthreads();
    if (tid < GBK - 1) {                        // 511 threads poll 511 flags in parallel
      const unsigned* fl = bar + tid * 4;
      while (aload(fl) < n) __builtin_amdgcn_s_sleep(1);
    }
    __syncthreads();
    if (tid == 0) {
      astore(bar + BAR_GGEN, n);
      astore(bar + BAR_LGEN + (NGRP - 1) * 64, n);
    }
  } else {
    if (tid == 0) {
      const int g = bid / GRPSZ;
      __builtin_amdgcn_fence(__ATOMIC_RELEASE, "agent");
      astore(bar + bid * 4, n);                 // own flag, no contention
      if ((bid % GRPSZ) == 0) {                 // relay block
        while (aload(bar + BAR_GGEN) < n) __builtin_amdgcn_s_sleep(1);
        astore(bar + BAR_LGEN + g * 64, n);
      } else {
        while (aload(bar + BAR_LGEN + g * 64) < n) __builtin_amdgcn_s_sleep(2);
      }
    }
    __syncthreads();
  }
}

// ---------- prep kernels ----------
__global__ void conv_bf16(const float* __restrict__ src, ushortT* __restrict__ dst, size_t n) {
  size_t i  = blockIdx.x * (size_t)blockDim.x + threadIdx.x;
  size_t st = (size_t)gridDim.x * blockDim.x;
  for (; i < n; i += st) dst[i] = f2bf(src[i]);
}

__global__ void prep_kv(const float* __restrict__ text, const float* __restrict__ Wk,
                        const float* __restrict__ Wv, ushortT* __restrict__ keys,
                        ushortT* __restrict__ vals) {
  __shared__ float tx[ATT];
  const int t = blockIdx.x;
  for (int i = threadIdx.x; i < ATT; i += blockDim.x) tx[i] = text[(size_t)t*ATT + i];
  __syncthreads();
  for (int a = threadIdx.x; a < 2*ATT; a += blockDim.x) {
    const int which = (a >= ATT);
    const int ar = a - which*ATT;
    const float4* w4 = (const float4*)((which ? Wv : Wk) + (size_t)ar*ATT);
    const float4* t4 = (const float4*)tx;
    float s = 0.f;
    for (int i = 0; i < ATT/4; ++i) {
      float4 w = w4[i], x = t4[i];
      s += w.x*x.x + w.y*x.y + w.z*x.z + w.w*x.w;
    }
    (which ? vals : keys)[(size_t)t*ATT + ar] = f2bf(s);
  }
}

__global__ void prep_zero(float* f, unsigned* bar) {
  int i = blockIdx.x * blockDim.x + threadIdx.x;
  if (i < F_END) f[i] = 0.f;
  if (i < BAR_N) bar[i] = 0u;
}

// ---------- persistent AR kernel ----------
__global__ void __launch_bounds__(NT, 4)
ar_persist(const float* __restrict__ residual,
           const float* __restrict__ Whh_a, const float* __restrict__ Whh0g,
           const float* __restrict__ Wih1g,
           const float* __restrict__ b_a, const float* __restrict__ v_attn,
           const float* __restrict__ b0, const float* __restrict__ b1,
           const float* __restrict__ bd1, const float* __restrict__ bd2,
           const float* __restrict__ Wc, const float* __restrict__ bc,
           const float* __restrict__ Wg, const float* __restrict__ bg,
           float* __restrict__ out, void* __restrict__ wsraw)
{
  const int tid  = threadIdx.x;
  const int bid  = blockIdx.x;
  const int wid  = tid >> 6;     // 8 waves
  const int lane = tid & 63;

  const ushortT* uws = (const ushortT*)wsraw;
  float*    f   = (float*)((char*)wsraw + FBYTE);
  unsigned* bar = (unsigned*)((char*)wsraw + BBYTE);

  const ushortT* wq    = uws + O_WQ;
  const ushortT* wiha  = uws + O_WIHA;
  const ushortT* wih0  = uws + O_WIH0;
  const ushortT* whh1s = uws + O_WHH1;
  const ushortT* wd1   = uws + O_WD1;
  const ushortT* wd2   = uws + O_WD2;
  const ushortT* keys  = uws + O_KEYS;
  const ushortT* vals  = uws + O_VALS;

  // this block: hidden units {2*bid, 2*bid+1}; wave wid -> gate gi of hidden hj
  const int hj = wid >> 2, gi = wid & 3;
  const int zrow = gi*H + bid*2 + hj;           // row of the 4H-dim z

  __shared__ ushortT lWhha[8*H];    // 16 KB each
  __shared__ ushortT lWih0H[8*H];
  __shared__ ushortT lWhh0[8*H];
  __shared__ ushortT lWih1[8*H];
  __shared__ float   shv[2048];
  __shared__ float   lctx[ATT];     // q (P3) / ctx (P4)
  __shared__ float   zl[8], zp[8], sc[32], cells[6], misc2[4], sAMZ[16];

  // ---- stage this block's recurrent rows into LDS (us4 layout matches dotbf) ----
  {
    us4* dA = (us4*)lWhha;  us4* dB = (us4*)lWih0H;
    us4* dC = (us4*)lWhh0;  us4* dD = (us4*)lWih1;
    const us4* s0 = (const us4*)wih0;
    #pragma unroll
    for (int c = 0; c < 4; ++c) {
      const int ei = c*64 + lane;                  // float4 / us4 index in row
      dA[wid*256 + ei] = cvt4(*(const float4*)(Whh_a + (size_t)zrow*H + ei*4));
      dC[wid*256 + ei] = cvt4(*(const float4*)(Whh0g + (size_t)zrow*H + ei*4));
      dD[wid*256 + ei] = cvt4(*(const float4*)(Wih1g + (size_t)zrow*H + ei*4));
      dB[wid*256 + ei] = s0[(size_t)zrow*416 + ei];   // Wih0 H-part (already bf16)
    }
  }
  if (tid < 6) cells[tid] = 0.f;
  __syncthreads();

  int pa = 0, p1 = 0;
  unsigned nb = 0;   // barrier epoch (monotonic)

  for (int s = 0; s < T_STEPS; ++s) {
    // ===== P1: z_a = Wih_a@x + Whh_a@ha + b_a -> ha, ca =====
    cstage(shv, f + F_X, 80);
    cstage(shv + 128, f + F_HA + pa*H, H);
    __syncthreads();
    {
      float s1 = 0.f;
      if (lane < 20) {
        us4 w = ((const us4*)wiha)[(size_t)zrow*20 + lane];
        float4 xv = ((const float4*)shv)[lane];
        s1 = bf2f(w[0])*xv.x + bf2f(w[1])*xv.y + bf2f(w[2])*xv.z + bf2f(w[3])*xv.w;
      }
      s1 += dotbf(lWhha + wid*H, shv + 128, lane);
      s1 = red64(s1) + b_a[zrow];
      if (lane == 0) zl[wid] = s1;
    }
    __syncthreads();
    if (tid < 2) {
      float iv = zl[tid*4+0], fv = zl[tid*4+1], gv = zl[tid*4+2], ov = zl[tid*4+3];
      float c = sigf(fv)*cells[tid] + sigf(iv)*tanhf(gv);
      float h = sigf(ov)*tanhf(c);
      cells[tid] = c;
      cstore(f + F_HA + (pa^1)*H + bid*2 + tid, h);
    }
    pa ^= 1;
    gridbar(bar, bid, ++nb);

    // ===== P2: z0part = Wih0[:,:H]@ha + Whh0@h0 + b0 ; q rows ; gate_ha =====
    cstage(shv, f + F_HA + pa*H, H);
    cstage(shv + 1024, f + F_H0, H);
    __syncthreads();
    {
      float s2 = dotbf(lWih0H + wid*H, shv, lane)
               + dotbf(lWhh0 + wid*H, shv + 1024, lane);
      s2 = red64(s2) + b0[zrow];
      if (lane == 0) zp[wid] = s2;
      if (wid == 0) {                       // q row bid
        float sq = dotbf(wq + (size_t)bid*H, shv, lane);
        sq = red64(sq);
        if (lane == 0) cstore(f + F_Q + bid, sq);
      }
      if (wid == 1 && bid < ATT - GBK) {    // q rows 512..639
        const int qr = GBK + bid;
        float sq = dotbf(wq + (size_t)qr*H, shv, lane);
        sq = red64(sq);
        if (lane == 0) cstore(f + F_Q + qr, sq);
      }
      if (bid == GATE_B && wid == 2) {      // gate ha-part (fp32 Wg)
        float sg = dotf(Wg, shv, lane);
        sg = red64(sg);
        if (lane == 0) misc2[0] = sg;
      }
    }
    gridbar(bar, bid, ++nb);

    // ===== P3: attention partials (blocks 0..7 x 25 positions) =====
    if (bid < 8) {
      cstage(lctx, f + F_Q, ATT);
      __syncthreads();
      for (int pl = wid; pl < 25; pl += 8) {
        const int t = bid*25 + pl;
        float ss = 0.f;
        #pragma unroll
        for (int i = 0; i < 10; ++i) {
          const int idx = lane + 64*i;
          ss += tanhf(bf2f(keys[(size_t)t*ATT + idx]) + lctx[idx]) * v_attn[idx];
        }
        ss = red64(ss);
        if (lane == 0) sc[pl] = ss;
      }
      __syncthreads();
      if (tid == 0) {
        float m = sc[0];
        for (int i = 1; i < 25; ++i) m = fmaxf(m, sc[i]);
        misc2[1] = m;
      }
      __syncthreads();
      if (tid < 25) sc[tid] = expf(sc[tid] - misc2[1]);
      __syncthreads();
      if (tid == 0) {
        float z = 0.f;
        for (int i = 0; i < 25; ++i) z += sc[i];
        cstore(f + F_AM + bid, misc2[1]);
        cstore(f + F_AZ + bid, z);
      }
      for (int a = tid; a < ATT; a += NT) {
        float acc = 0.f;
        for (int i = 0; i < 25; ++i)
          acc += sc[i] * bf2f(vals[(size_t)(bid*25 + i)*ATT + a]);
        cstore(f + F_CP + bid*ATT + a, acc);
      }
    }
    gridbar(bar, bid, ++nb);

    // ===== P4: ctx combine -> LDS ; z0 finish -> h0 ; gate out =====
    if (tid < 16) sAMZ[tid] = cload(f + F_AM + tid);   // 8 max + 8 sumexp
    __syncthreads();
    {
      float m = sAMZ[0];
      #pragma unroll
      for (int i = 1; i < 8; ++i) m = fmaxf(m, sAMZ[i]);
      float wgt[8]; float Zt = 0.f;
      #pragma unroll
      for (int i = 0; i < 8; ++i) {
        wgt[i] = expf(sAMZ[i] - m);
        Zt += wgt[i] * sAMZ[8 + i];
      }
      const float inv = 1.0f / Zt;
      for (int a = tid; a < ATT; a += NT) {
        float c = 0.f;
        #pragma unroll
        for (int p = 0; p < 8; ++p) c += wgt[p] * cload(f + F_CP + p*ATT + a);
        lctx[a] = c * inv;
      }
    }
    __syncthreads();
    {
      float s4 = dot640bf(wih0 + (size_t)zrow*DIN + H, lctx, lane);
      s4 = red64(s4) + zp[wid];
      if (lane == 0) zl[wid] = s4;
    }
    __syncthreads();
    if (tid < 2) {
      float iv = zl[tid*4+0], fv = zl[tid*4+1], gv = zl[tid*4+2], ov = zl[tid*4+3];
      float c = sigf(fv)*cells[2+tid] + sigf(iv)*tanhf(gv);
      float h = sigf(ov)*tanhf(c);
      cells[2+tid] = c;
      cstore(f + F_H0 + bid*2 + tid, h);
    }
    if (bid == GATE_B && wid == 3) {
      float sg = dot640f(Wg + H, lctx, lane);
      sg = red64(sg);
      if (lane == 0) out[T_STEPS*NMEL + s] = sigf(sg + misc2[0] + bg[0]);
    }
    gridbar(bar, bid, ++nb);

    // ===== P5: z1 = Wih1@h0 + Whh1@h1 + b1 -> h1 =====
    cstage(shv, f + F_H0, H);
    cstage(shv + 1024, f + F_H1 + p1*H, H);
    __syncthreads();
    {
      float s5 = dotbf(lWih1 + wid*H, shv, lane)
               + dotbf(whh1s + (size_t)zrow*H, shv + 1024, lane);
      s5 = red64(s5) + b1[zrow];
      if (lane == 0) zl[wid] = s5;
    }
    __syncthreads();
    if (tid < 2) {
      float iv = zl[tid*4+0], fv = zl[tid*4+1], gv = zl[tid*4+2], ov = zl[tid*4+3];
      float c = sigf(fv)*cells[4+tid] + sigf(iv)*tanhf(gv);
      float h = sigf(ov)*tanhf(c);
      cells[4+tid] = c;
      cstore(f + F_H1 + (p1^1)*H + bid*2 + tid, h);
    }
    p1 ^= 1;
    gridbar(bar, bid, ++nb);

    // ===== P6: d1 = tanh(Wd1@h1 + bd1) =====
    cstage(shv, f + F_H1 + p1*H, H);
    __syncthreads();
    if (wid < 2) {
      const int r = bid*2 + wid;
      float s6 = dotbf(wd1 + (size_t)r*H, shv, lane);
      s6 = red64(s6) + bd1[r];
      if (lane == 0) cstore(f + F_D1 + r, tanhf(s6));
    }
    gridbar(bar, bid, ++nb);

    // ===== P7: d = tanh(Wd2@d1 + bd2) =====
    cstage(shv, f + F_D1, H);
    __syncthreads();
    if (wid < 2) {
      const int r = bid*2 + wid;
      float s7 = dotbf(wd2 + (size_t)r*H, shv, lane);
      s7 = red64(s7) + bd2[r];
      if (lane == 0) cstore(f + F_D + r, tanhf(s7));
    }
    gridbar(bar, bid, ++nb);

    // ===== P8: dec_out rows (bid, 80+bid) ; out ; next x =====
    if (bid < NMEL) {
      cstage(shv, f + F_D, H);
      __syncthreads();
      if (wid < 2) {
        const int r = wid*NMEL + bid;   // wid0: log_s row, wid1: bb row
        float s8 = dotf(Wc + (size_t)r*H, shv, lane);
        s8 = red64(s8) + bc[r];
        if (lane == 0) misc2[2 + wid] = s8;
      }
      __syncthreads();
      if (tid == 0) {
        const int idx = T_STEPS - 1 - s;
        const float r = residual[idx*NMEL + bid];
        const float o = (r - misc2[3]) * expf(-misc2[2]);
        out[idx*NMEL + bid] = o;
        cstore(f + F_X + bid, o);
      }
    }
    gridbar(bar, bid, ++nb);
  }
}

extern "C" void kernel_launch(void* const* d_in, const int* in_sizes, int n_in,
                              void* d_out, int out_size, void* d_ws, size_t ws_size,
                              hipStream_t stream) {
  const float* residual = (const float*)d_in[0];
  const float* text   = (const float*)d_in[1];
  const float* Wih_a  = (const float*)d_in[2];
  const float* Whh_a  = (const float*)d_in[3];
  const float* b_a    = (const float*)d_in[4];
  const float* Wq     = (const float*)d_in[5];
  const float* Wk     = (const float*)d_in[6];
  const float* Wv     = (const float*)d_in[7];
  const float* v_attn = (const float*)d_in[8];
  const float* Wih0   = (const float*)d_in[9];
  const float* Whh0   = (const float*)d_in[10];
  const float* b0     = (const float*)d_in[11];
  const float* Wih1   = (const float*)d_in[12];
  const float* Whh1   = (const float*)d_in[13];
  const float* b1     = (const float*)d_in[14];
  const float* Wd1    = (const float*)d_in[15];
  const float* bd1    = (const float*)d_in[16];
  const float* Wd2    = (const float*)d_in[17];
  const float* bd2    = (const float*)d_in[18];
  const float* Wc     = (const float*)d_in[19];
  const float* bc     = (const float*)d_in[20];
  const float* Wg     = (const float*)d_in[21];
  const float* bg     = (const float*)d_in[22];
  float* out = (float*)d_out;

  char* wsb = (char*)d_ws;
  ushortT*  u   = (ushortT*)wsb;
  float*    f   = (float*)(wsb + FBYTE);
  unsigned* bar = (unsigned*)(wsb + BBYTE);

  conv_bf16<<<1024, 256, 0, stream>>>(Wq,    u + O_WQ,   (size_t)ATT*H);
  conv_bf16<<<1024, 256, 0, stream>>>(Wih_a, u + O_WIHA, (size_t)4*H*NMEL);
  conv_bf16<<<1024, 256, 0, stream>>>(Wih0,  u + O_WIH0, (size_t)4*H*DIN);
  conv_bf16<<<1024, 256, 0, stream>>>(Whh1,  u + O_WHH1, (size_t)4*H*H);
  conv_bf16<<<1024, 256, 0, stream>>>(Wd1,   u + O_WD1,  (size_t)H*H);
  conv_bf16<<<1024, 256, 0, stream>>>(Wd2,   u + O_WD2,  (size_t)H*H);
  prep_kv<<<TXT, 256, 0, stream>>>(text, Wk, Wv, u + O_KEYS, u + O_VALS);
  prep_zero<<<(F_END + 255)/256, 256, 0, stream>>>(f, bar);

  ar_persist<<<GBK, NT, 0, stream>>>(residual, Whh_a, Whh0, Wih1,
      b_a, v_attn, b0, b1, bd1, bd2, Wc, bc, Wg, bg, out, d_ws);
}